// Round 10
// baseline (107.505 us; speedup 1.0000x reference)
//
#include <hip/hip_runtime.h>
#include <math.h>

#define S_NEI 32

// ---------------- transpose 256x256 (WkT[e][f] = Wk[f][e]) ----------------
__global__ __launch_bounds__(256) void transpose256(const float* __restrict__ in,
                                                    float* __restrict__ outT) {
    __shared__ float tile[32][33];
    const int bx = blockIdx.x * 32, by = blockIdx.y * 32;
    const int x = threadIdx.x, y = threadIdx.y;  // 32 x 8
#pragma unroll
    for (int i = 0; i < 32; i += 8)
        tile[y + i][x] = in[(by + y + i) * 256 + bx + x];
    __syncthreads();
#pragma unroll
    for (int i = 0; i < 32; i += 8)
        outT[(bx + y + i) * 256 + by + x] = tile[x][y + i];
}

// ---------------- legacy 8x256 tile GEMM (for tiny precompute GEMMs) -------
template <int KT>
__device__ __forceinline__ void gemm_tile8(const float* __restrict__ A, int row0,
                                           const float* __restrict__ B,
                                           float acc[2][4], float* __restrict__ sA,
                                           float* __restrict__ sB) {
    const int t = threadIdx.x;
    const int tr = t >> 6, tc = t & 63;
    const int r = t >> 5;
    const int k1 = t & 31;
    const size_t arow = (size_t)(row0 + r) * KT;
    for (int kb = 0; kb < KT; kb += 32) {
        sA[k1 * 12 + r] = A[arow + kb + k1];
#pragma unroll
        for (int i = 0; i < 8; ++i) {
            *reinterpret_cast<float4*>(&sB[(i * 4 + tr) * 256 + tc * 4]) =
                *reinterpret_cast<const float4*>(&B[(size_t)(kb + i * 4 + tr) * 256 + tc * 4]);
        }
        __syncthreads();
#pragma unroll
        for (int k = 0; k < 32; ++k) {
            const float2 a2 = *reinterpret_cast<const float2*>(&sA[k * 12 + tr * 2]);
            const float4 b4 = *reinterpret_cast<const float4*>(&sB[k * 256 + tc * 4]);
            acc[0][0] += a2.x * b4.x; acc[0][1] += a2.x * b4.y;
            acc[0][2] += a2.x * b4.z; acc[0][3] += a2.x * b4.w;
            acc[1][0] += a2.y * b4.x; acc[1][1] += a2.y * b4.y;
            acc[1][2] += a2.y * b4.z; acc[1][3] += a2.y * b4.w;
        }
        __syncthreads();
    }
}

// Wqk=Wq@WkT, Wvc=Wv@Wc_top, Wmc=Wm@Wc_bot
__global__ __launch_bounds__(256) void precompute3(const float* __restrict__ Wq,
                                                   const float* __restrict__ Wv,
                                                   const float* __restrict__ Wm,
                                                   const float* __restrict__ Wc,
                                                   const float* __restrict__ WkT,
                                                   float* __restrict__ Wqk,
                                                   float* __restrict__ Wvc,
                                                   float* __restrict__ Wmc) {
    __shared__ float sA[32 * 12];
    __shared__ float sB[32 * 256];
    float acc[2][4] = {};
    const float *Ap, *Bp;
    float* Cp;
    switch (blockIdx.y) {
        case 0: Ap = Wq; Bp = WkT; Cp = Wqk; break;
        case 1: Ap = Wv; Bp = Wc; Cp = Wvc; break;
        default: Ap = Wm; Bp = Wc + 256 * 256; Cp = Wmc; break;
    }
    const int row0 = blockIdx.x * 8;
    gemm_tile8<256>(Ap, row0, Bp, acc, sA, sB);
    const int tr = threadIdx.x >> 6, tc = threadIdx.x & 63;
#pragma unroll
    for (int i = 0; i < 2; ++i) {
        float4 v = make_float4(acc[i][0], acc[i][1], acc[i][2], acc[i][3]);
        *reinterpret_cast<float4*>(&Cp[(row0 + tr * 2 + i) * 256 + tc * 4]) = v;
    }
}

// bqk = bq@WkT ; bfull = bv@Wc_top + bm@Wc_bot + bc  (block per column)
__global__ __launch_bounds__(256) void bias_k(const float* __restrict__ bq,
                                              const float* __restrict__ bv,
                                              const float* __restrict__ bm,
                                              const float* __restrict__ bc,
                                              const float* __restrict__ Wc,
                                              const float* __restrict__ WkT,
                                              float* __restrict__ bqk,
                                              float* __restrict__ bfull) {
    const int c = blockIdx.x;
    const int e = threadIdx.x;
    const int w = e >> 6, l = e & 63;
    float a = bq[e] * WkT[e * 256 + c];
    float v = bv[e] * Wc[e * 256 + c] + bm[e] * Wc[(256 + e) * 256 + c];
    __shared__ float redA[4], redV[4];
#pragma unroll
    for (int off = 32; off; off >>= 1) { a += __shfl_xor(a, off); v += __shfl_xor(v, off); }
    if (l == 0) { redA[w] = a; redV[w] = v; }
    __syncthreads();
    if (e == 0) {
        bqk[c] = redA[0] + redA[1] + redA[2] + redA[3];
        bfull[c] = bc[c] + redV[0] + redV[1] + redV[2] + redV[3];
    }
}

// ---------------- wave-level FMA: 8 rows x 2 cols --------------------------
#define FMAB(a0, a1, b2)                                                    \
    do {                                                                    \
        acc[0][0] += (a0).x * (b2).x; acc[0][1] += (a0).x * (b2).y;         \
        acc[1][0] += (a0).y * (b2).x; acc[1][1] += (a0).y * (b2).y;         \
        acc[2][0] += (a0).z * (b2).x; acc[2][1] += (a0).z * (b2).y;         \
        acc[3][0] += (a0).w * (b2).x; acc[3][1] += (a0).w * (b2).y;         \
        acc[4][0] += (a1).x * (b2).x; acc[4][1] += (a1).x * (b2).y;         \
        acc[5][0] += (a1).y * (b2).x; acc[5][1] += (a1).y * (b2).y;         \
        acc[6][0] += (a1).z * (b2).x; acc[6][1] += (a1).z * (b2).y;         \
        acc[7][0] += (a1).w * (b2).x; acc[7][1] += (a1).w * (b2).y;         \
    } while (0)

// ---------------- Qk = id2feat[nodes](8x256) @ Wqk + bqk -------------------
// 512 thr = 8 waves: g = w>>2 column-half (128 cols, lane owns 2), kq = w&3
// K-quarter. Per-wave B-stream = 64k x 128c x 4B = 32 KB. sA word = k*8+r.
__global__ __launch_bounds__(512, 2) void qk8(const float* __restrict__ id2feat,
                                              const int* __restrict__ nodes,
                                              const float* __restrict__ Wqk,
                                              const float* __restrict__ bqk,
                                              float* __restrict__ Qk) {
    __shared__ float sA[256 * 8];        // 8 KB, word = k*8 + r
    __shared__ float sP[6 * 8 * 132];    // ~25 KB partials [(g*3+kq-1)*8+row][132]
    const int t = threadIdx.x;
    const int w = t >> 6, l = t & 63;
    const int g = w >> 2, kq = w & 3;
    const int c0 = g * 128 + l * 2;
    const int row0 = blockIdx.x * 8;

    // stage A transposed: thread t stages 4 k's of row t&7
    {
        const int r = t & 7, k0 = (t >> 3) << 2;
        const float4 v = *reinterpret_cast<const float4*>(
            &id2feat[(size_t)nodes[row0 + r] * 256 + k0]);
        sA[(k0 + 0) * 8 + r] = v.x;
        sA[(k0 + 1) * 8 + r] = v.y;
        sA[(k0 + 2) * 8 + r] = v.z;
        sA[(k0 + 3) * 8 + r] = v.w;
    }
    __syncthreads();

    float acc[8][2] = {};
    {
        const float* Bp = Wqk + (size_t)(kq * 64) * 256 + c0;
        float2 bufA[8], bufB[8];
#pragma unroll
        for (int j = 0; j < 8; ++j)
            bufA[j] = *reinterpret_cast<const float2*>(&Bp[(size_t)j * 256]);
        for (int kb = 0; kb < 64; kb += 16) {
#pragma unroll
            for (int j = 0; j < 8; ++j)
                bufB[j] = *reinterpret_cast<const float2*>(&Bp[(size_t)(kb + 8 + j) * 256]);
#pragma unroll
            for (int j = 0; j < 8; ++j) {
                const int k = kq * 64 + kb + j;
                const float4 a0 = *reinterpret_cast<const float4*>(&sA[k * 8]);
                const float4 a1 = *reinterpret_cast<const float4*>(&sA[k * 8 + 4]);
                FMAB(a0, a1, bufA[j]);
            }
            if (kb + 16 < 64) {
#pragma unroll
                for (int j = 0; j < 8; ++j)
                    bufA[j] = *reinterpret_cast<const float2*>(&Bp[(size_t)(kb + 16 + j) * 256]);
            }
#pragma unroll
            for (int j = 0; j < 8; ++j) {
                const int k = kq * 64 + kb + 8 + j;
                const float4 a0 = *reinterpret_cast<const float4*>(&sA[k * 8]);
                const float4 a1 = *reinterpret_cast<const float4*>(&sA[k * 8 + 4]);
                FMAB(a0, a1, bufB[j]);
            }
        }
    }
    if (kq) {
        float* p = sP + ((g * 3 + kq - 1) * 8) * 132 + l * 2;
#pragma unroll
        for (int r = 0; r < 8; ++r) {
            p[r * 132 + 0] = acc[r][0];
            p[r * 132 + 1] = acc[r][1];
        }
    }
    __syncthreads();
    if (kq == 0) {
        const float2 b2 = *reinterpret_cast<const float2*>(&bqk[c0]);
#pragma unroll
        for (int r = 0; r < 8; ++r) {
            float v0 = acc[r][0] + b2.x, v1 = acc[r][1] + b2.y;
#pragma unroll
            for (int s = 0; s < 3; ++s) {
                const float* p = sP + ((g * 3 + s) * 8 + r) * 132 + l * 2;
                v0 += p[0]; v1 += p[1];
            }
            *reinterpret_cast<float2*>(&Qk[(size_t)(row0 + r) * 256 + c0]) =
                make_float2(v0, v1);
        }
    }
}

// ---------------- per-node: neighbor mean + attention-weighted sum ---------
// (R5's proven high-occupancy kernel: grid B, 1 node/block, rows in registers)
__global__ __launch_bounds__(256) void mean_attn(const float* __restrict__ id2feat,
                                                 const int* __restrict__ neigh_mean,
                                                 const int* __restrict__ neigh_attn,
                                                 const float* __restrict__ Qk,
                                                 float* __restrict__ AF) {
    const int b = blockIdx.x;
    const int t = threadIdx.x;
    const int w = t >> 6, l = t & 63;
    __shared__ int sIA[S_NEI], sIM[S_NEI];
    __shared__ float sS[S_NEI];
    __shared__ float4 sRed[2][4][64];  // 8 KB

    if (t < S_NEI) sIA[t] = neigh_attn[b * S_NEI + t];
    else if (t < 2 * S_NEI) sIM[t - S_NEI] = neigh_mean[b * S_NEI + (t - S_NEI)];
    __syncthreads();

    const float4* f4 = reinterpret_cast<const float4*>(id2feat);  // row = 64 float4
    float4 r[8];
#pragma unroll
    for (int j = 0; j < 8; ++j) r[j] = f4[(size_t)sIA[w * 8 + j] * 64 + l];
    float4 macc = make_float4(0.f, 0.f, 0.f, 0.f);
#pragma unroll
    for (int j = 0; j < 8; ++j) {
        const float4 v = f4[(size_t)sIM[w * 8 + j] * 64 + l];
        macc.x += v.x; macc.y += v.y; macc.z += v.z; macc.w += v.w;
    }
    const float4 q = reinterpret_cast<const float4*>(Qk + (size_t)b * 256)[l];

#pragma unroll
    for (int j = 0; j < 8; ++j) {
        float p = q.x * r[j].x + q.y * r[j].y + q.z * r[j].z + q.w * r[j].w;
#pragma unroll
        for (int off = 32; off; off >>= 1) p += __shfl_xor(p, off);
        if (l == 0) sS[w * 8 + j] = p;
    }
    __syncthreads();

    float m = -1e30f;
#pragma unroll
    for (int s = 0; s < S_NEI; ++s) m = fmaxf(m, sS[s]);
    float sum = 0.f;
#pragma unroll
    for (int s = 0; s < S_NEI; ++s) sum += __expf(sS[s] - m);
    const float inv = 1.0f / sum;

    float4 wa = make_float4(0.f, 0.f, 0.f, 0.f);
#pragma unroll
    for (int j = 0; j < 8; ++j) {
        const float wgt = __expf(sS[w * 8 + j] - m);
        wa.x += wgt * r[j].x; wa.y += wgt * r[j].y; wa.z += wgt * r[j].z; wa.w += wgt * r[j].w;
    }
    sRed[0][w][l] = wa;
    sRed[1][w][l] = macc;
    __syncthreads();

    float4* AF4 = reinterpret_cast<float4*>(AF) + (size_t)b * 128;  // 128 float4/row
    if (t < 64) {
        const float4 a0 = sRed[0][0][t], a1 = sRed[0][1][t], a2 = sRed[0][2][t], a3 = sRed[0][3][t];
        AF4[t] = make_float4((a0.x + a1.x + a2.x + a3.x) * inv,
                             (a0.y + a1.y + a2.y + a3.y) * inv,
                             (a0.z + a1.z + a2.z + a3.z) * inv,
                             (a0.w + a1.w + a2.w + a3.w) * inv);
    } else if (t < 128) {
        const int g = t - 64;
        const float4 a0 = sRed[1][0][g], a1 = sRed[1][1][g], a2 = sRed[1][2][g], a3 = sRed[1][3][g];
        const float sc = 1.0f / S_NEI;
        AF4[64 + g] = make_float4((a0.x + a1.x + a2.x + a3.x) * sc,
                                  (a0.y + a1.y + a2.y + a3.y) * sc,
                                  (a0.z + a1.z + a2.z + a3.z) * sc,
                                  (a0.w + a1.w + a2.w + a3.w) * sc);
    }
}

// ---------------- out = normalize(tanh(AF(8x512) @ Wfused + bfull)) --------
// Same geometry as qk8; KT=512 -> per-wave B-stream 64 KB.
__global__ __launch_bounds__(512, 2) void fin8(const float* __restrict__ AF,
                                               const float* __restrict__ Wfused,
                                               const float* __restrict__ bfull,
                                               float* __restrict__ out) {
    __shared__ float sA[512 * 8];        // 16 KB, word = k*8 + r
    __shared__ float sP[6 * 8 * 132];    // ~25 KB
    __shared__ float sN[2][8];
    const int t = threadIdx.x;
    const int w = t >> 6, l = t & 63;
    const int g = w >> 2, kq = w & 3;
    const int c0 = g * 128 + l * 2;
    const int row0 = blockIdx.x * 8;

    // stage AF transposed: thread t stages 8 k's of row t&7
    {
        const int r = t & 7, k0 = (t >> 3) << 3;
        const float* src = &AF[(size_t)(row0 + r) * 512 + k0];
        const float4 v0 = *reinterpret_cast<const float4*>(src);
        const float4 v1 = *reinterpret_cast<const float4*>(src + 4);
        sA[(k0 + 0) * 8 + r] = v0.x; sA[(k0 + 1) * 8 + r] = v0.y;
        sA[(k0 + 2) * 8 + r] = v0.z; sA[(k0 + 3) * 8 + r] = v0.w;
        sA[(k0 + 4) * 8 + r] = v1.x; sA[(k0 + 5) * 8 + r] = v1.y;
        sA[(k0 + 6) * 8 + r] = v1.z; sA[(k0 + 7) * 8 + r] = v1.w;
    }
    __syncthreads();

    float acc[8][2] = {};
    {
        const float* Bp = Wfused + (size_t)(kq * 128) * 256 + c0;
        float2 bufA[8], bufB[8];
#pragma unroll
        for (int j = 0; j < 8; ++j)
            bufA[j] = *reinterpret_cast<const float2*>(&Bp[(size_t)j * 256]);
        for (int kb = 0; kb < 128; kb += 16) {
#pragma unroll
            for (int j = 0; j < 8; ++j)
                bufB[j] = *reinterpret_cast<const float2*>(&Bp[(size_t)(kb + 8 + j) * 256]);
#pragma unroll
            for (int j = 0; j < 8; ++j) {
                const int k = kq * 128 + kb + j;
                const float4 a0 = *reinterpret_cast<const float4*>(&sA[k * 8]);
                const float4 a1 = *reinterpret_cast<const float4*>(&sA[k * 8 + 4]);
                FMAB(a0, a1, bufA[j]);
            }
            if (kb + 16 < 128) {
#pragma unroll
                for (int j = 0; j < 8; ++j)
                    bufA[j] = *reinterpret_cast<const float2*>(&Bp[(size_t)(kb + 16 + j) * 256]);
            }
#pragma unroll
            for (int j = 0; j < 8; ++j) {
                const int k = kq * 128 + kb + 8 + j;
                const float4 a0 = *reinterpret_cast<const float4*>(&sA[k * 8]);
                const float4 a1 = *reinterpret_cast<const float4*>(&sA[k * 8 + 4]);
                FMAB(a0, a1, bufB[j]);
            }
        }
    }
    if (kq) {
        float* p = sP + ((g * 3 + kq - 1) * 8) * 132 + l * 2;
#pragma unroll
        for (int r = 0; r < 8; ++r) {
            p[r * 132 + 0] = acc[r][0];
            p[r * 132 + 1] = acc[r][1];
        }
    }
    __syncthreads();

    float vv[8][2];
    if (kq == 0) {
        const float2 b2 = *reinterpret_cast<const float2*>(&bfull[c0]);
#pragma unroll
        for (int r = 0; r < 8; ++r) {
            float v0 = acc[r][0] + b2.x, v1 = acc[r][1] + b2.y;
#pragma unroll
            for (int s = 0; s < 3; ++s) {
                const float* p = sP + ((g * 3 + s) * 8 + r) * 132 + l * 2;
                v0 += p[0]; v1 += p[1];
            }
            vv[r][0] = tanhf(v0);
            vv[r][1] = tanhf(v1);
            float sq = vv[r][0] * vv[r][0] + vv[r][1] * vv[r][1];
#pragma unroll
            for (int off = 32; off; off >>= 1) sq += __shfl_xor(sq, off);
            if (l == 0) sN[g][r] = sq;  // partial norm over this col-half
        }
    }
    __syncthreads();
    if (kq == 0) {
#pragma unroll
        for (int r = 0; r < 8; ++r) {
            const float invn = 1.0f / fmaxf(sqrtf(sN[0][r] + sN[1][r]), 1e-12f);
            *reinterpret_cast<float2*>(&out[(size_t)(row0 + r) * 256 + c0]) =
                make_float2(vv[r][0] * invn, vv[r][1] * invn);
        }
    }
}

extern "C" void kernel_launch(void* const* d_in, const int* in_sizes, int n_in,
                              void* d_out, int out_size, void* d_ws, size_t ws_size,
                              hipStream_t stream) {
    const int* nodes      = (const int*)d_in[0];
    const int* neigh_mean = (const int*)d_in[1];
    const int* neigh_attn = (const int*)d_in[2];
    const float* id2feat  = (const float*)d_in[3];
    const float* Wm = (const float*)d_in[4];
    const float* bm = (const float*)d_in[5];
    const float* Wq = (const float*)d_in[6];
    const float* bq = (const float*)d_in[7];
    const float* Wk = (const float*)d_in[8];
    // d_in[9] = bk: cancels in softmax
    const float* Wv = (const float*)d_in[10];
    const float* bv = (const float*)d_in[11];
    const float* Wc = (const float*)d_in[12];
    const float* bc = (const float*)d_in[13];
    float* out = (float*)d_out;

    const int B = in_sizes[0];  // 4096

    float* ws    = (float*)d_ws;
    float* WkT   = ws;                 // 65536
    float* Wqk   = ws + 65536;         // 65536
    float* Wvc   = ws + 131072;        // 65536 } contiguous Wfused[512][256]
    float* Wmc   = ws + 196608;        // 65536 }
    float* bqk   = ws + 262144;        // 256
    float* bfull = ws + 262400;        // 256
    float* Qk    = ws + 262656;        // B*256
    float* AF    = ws + 262656 + B * 256;  // B*512

    transpose256<<<dim3(8, 8), dim3(32, 8), 0, stream>>>(Wk, WkT);
    precompute3<<<dim3(32, 3), 256, 0, stream>>>(Wq, Wv, Wm, Wc, WkT, Wqk, Wvc, Wmc);
    bias_k<<<256, 256, 0, stream>>>(bq, bv, bm, bc, Wc, WkT, bqk, bfull);
    qk8<<<B / 8, 512, 0, stream>>>(id2feat, nodes, Wqk, bqk, Qk);
    mean_attn<<<B, 256, 0, stream>>>(id2feat, neigh_mean, neigh_attn, Qk, AF);
    fin8<<<B / 8, 512, 0, stream>>>(AF, Wvc /*Wfused*/, bfull, out);
}

// Round 11
// 89.939 us; speedup vs baseline: 1.1953x; 1.1953x over previous
//
#include <hip/hip_runtime.h>
#include <math.h>

#define S_NEI 32

// ---------------- transpose 256x256 (WkT[e][f] = Wk[f][e]) ----------------
__global__ __launch_bounds__(256) void transpose256(const float* __restrict__ in,
                                                    float* __restrict__ outT) {
    __shared__ float tile[32][33];
    const int bx = blockIdx.x * 32, by = blockIdx.y * 32;
    const int x = threadIdx.x, y = threadIdx.y;  // 32 x 8
#pragma unroll
    for (int i = 0; i < 32; i += 8)
        tile[y + i][x] = in[(by + y + i) * 256 + bx + x];
    __syncthreads();
#pragma unroll
    for (int i = 0; i < 32; i += 8)
        outT[(bx + y + i) * 256 + by + x] = tile[x][y + i];
}

// ---------------- legacy 8x256 tile GEMM (for tiny precompute GEMMs) -------
template <int KT>
__device__ __forceinline__ void gemm_tile8(const float* __restrict__ A, int row0,
                                           const float* __restrict__ B,
                                           float acc[2][4], float* __restrict__ sA,
                                           float* __restrict__ sB) {
    const int t = threadIdx.x;
    const int tr = t >> 6, tc = t & 63;
    const int r = t >> 5;
    const int k1 = t & 31;
    const size_t arow = (size_t)(row0 + r) * KT;
    for (int kb = 0; kb < KT; kb += 32) {
        sA[k1 * 12 + r] = A[arow + kb + k1];
#pragma unroll
        for (int i = 0; i < 8; ++i) {
            *reinterpret_cast<float4*>(&sB[(i * 4 + tr) * 256 + tc * 4]) =
                *reinterpret_cast<const float4*>(&B[(size_t)(kb + i * 4 + tr) * 256 + tc * 4]);
        }
        __syncthreads();
#pragma unroll
        for (int k = 0; k < 32; ++k) {
            const float2 a2 = *reinterpret_cast<const float2*>(&sA[k * 12 + tr * 2]);
            const float4 b4 = *reinterpret_cast<const float4*>(&sB[k * 256 + tc * 4]);
            acc[0][0] += a2.x * b4.x; acc[0][1] += a2.x * b4.y;
            acc[0][2] += a2.x * b4.z; acc[0][3] += a2.x * b4.w;
            acc[1][0] += a2.y * b4.x; acc[1][1] += a2.y * b4.y;
            acc[1][2] += a2.y * b4.z; acc[1][3] += a2.y * b4.w;
        }
        __syncthreads();
    }
}

// Wqk=Wq@WkT, Wvc=Wv@Wc_top, Wmc=Wm@Wc_bot
__global__ __launch_bounds__(256) void precompute3(const float* __restrict__ Wq,
                                                   const float* __restrict__ Wv,
                                                   const float* __restrict__ Wm,
                                                   const float* __restrict__ Wc,
                                                   const float* __restrict__ WkT,
                                                   float* __restrict__ Wqk,
                                                   float* __restrict__ Wvc,
                                                   float* __restrict__ Wmc) {
    __shared__ float sA[32 * 12];
    __shared__ float sB[32 * 256];
    float acc[2][4] = {};
    const float *Ap, *Bp;
    float* Cp;
    switch (blockIdx.y) {
        case 0: Ap = Wq; Bp = WkT; Cp = Wqk; break;
        case 1: Ap = Wv; Bp = Wc; Cp = Wvc; break;
        default: Ap = Wm; Bp = Wc + 256 * 256; Cp = Wmc; break;
    }
    const int row0 = blockIdx.x * 8;
    gemm_tile8<256>(Ap, row0, Bp, acc, sA, sB);
    const int tr = threadIdx.x >> 6, tc = threadIdx.x & 63;
#pragma unroll
    for (int i = 0; i < 2; ++i) {
        float4 v = make_float4(acc[i][0], acc[i][1], acc[i][2], acc[i][3]);
        *reinterpret_cast<float4*>(&Cp[(row0 + tr * 2 + i) * 256 + tc * 4]) = v;
    }
}

// bqk = bq@WkT ; bfull = bv@Wc_top + bm@Wc_bot + bc  (block per column)
__global__ __launch_bounds__(256) void bias_k(const float* __restrict__ bq,
                                              const float* __restrict__ bv,
                                              const float* __restrict__ bm,
                                              const float* __restrict__ bc,
                                              const float* __restrict__ Wc,
                                              const float* __restrict__ WkT,
                                              float* __restrict__ bqk,
                                              float* __restrict__ bfull) {
    const int c = blockIdx.x;
    const int e = threadIdx.x;
    const int w = e >> 6, l = e & 63;
    float a = bq[e] * WkT[e * 256 + c];
    float v = bv[e] * Wc[e * 256 + c] + bm[e] * Wc[(256 + e) * 256 + c];
    __shared__ float redA[4], redV[4];
#pragma unroll
    for (int off = 32; off; off >>= 1) { a += __shfl_xor(a, off); v += __shfl_xor(v, off); }
    if (l == 0) { redA[w] = a; redV[w] = v; }
    __syncthreads();
    if (e == 0) {
        bqk[c] = redA[0] + redA[1] + redA[2] + redA[3];
        bfull[c] = bc[c] + redV[0] + redV[1] + redV[2] + redV[3];
    }
}

// ---------------- fused per-4-node megakernel (R9 base + phase overlap) ----
// Wave w = K-quarter AND owns node b=w. Lane owns 4 cols.
// Phase 1: Qk GEMM with mean-gathers interleaved (independent of Qk).
// Phase 2: attn scores + weighted sum, double-buffered 8-row chunks;
//          chunk 0 prefetched before the Qk-combine barriers.
// Phase 3: final GEMM; B prologue prefetched before the sAF barrier.
// __launch_bounds__(256,2): min-waves>=4 forces 64-VGPR + scratch spill
// (R7/R8 evidence). Keep total VGPR <= 128 for 4 waves/SIMD.

#define SAF4(k) ((k) * 4 + ((((k) >> 3)) << 2))

#define FMA44(a4, b4)                                                       \
    do {                                                                    \
        acc[0][0] += (a4).x * (b4).x; acc[0][1] += (a4).x * (b4).y;         \
        acc[0][2] += (a4).x * (b4).z; acc[0][3] += (a4).x * (b4).w;         \
        acc[1][0] += (a4).y * (b4).x; acc[1][1] += (a4).y * (b4).y;         \
        acc[1][2] += (a4).y * (b4).z; acc[1][3] += (a4).y * (b4).w;         \
        acc[2][0] += (a4).z * (b4).x; acc[2][1] += (a4).z * (b4).y;         \
        acc[2][2] += (a4).z * (b4).z; acc[2][3] += (a4).z * (b4).w;         \
        acc[3][0] += (a4).w * (b4).x; acc[3][1] += (a4).w * (b4).y;         \
        acc[3][2] += (a4).w * (b4).z; acc[3][3] += (a4).w * (b4).w;         \
    } while (0)

__global__ __launch_bounds__(256, 2) void fused4(const float* __restrict__ id2feat,
                                                 const int* __restrict__ nodes,
                                                 const int* __restrict__ neigh_mean,
                                                 const int* __restrict__ neigh_attn,
                                                 const float* __restrict__ Wqk,
                                                 const float* __restrict__ bqk,
                                                 const float* __restrict__ Wfused,
                                                 const float* __restrict__ bfull,
                                                 float* __restrict__ out) {
    __shared__ __align__(16) char smem[18112];
    float* R0  = (float*)smem;               // 3120 floats: sA / sP / sAF aliased
    float* sQk = (float*)(smem + 12480);     // 1040 floats
    int*   sIA = (int*)(smem + 16640);       // 128
    int*   sIM = (int*)(smem + 17152);       // 128

    const int t = threadIdx.x;   // 256
    const int w = t >> 6, l = t & 63;
    const int kq = w;
    const int col4 = l * 4;
    const int row0 = blockIdx.x * 4;

    if (t < 128) sIA[t] = neigh_attn[(size_t)row0 * S_NEI + t];
    else sIM[t - 128] = neigh_mean[(size_t)row0 * S_NEI + (t - 128)];

    // stage 4 self rows transposed: wave w reads row w coalesced
    {
        const float4 v = *reinterpret_cast<const float4*>(
            &id2feat[(size_t)nodes[row0 + w] * 256 + col4]);
        R0[SAF4(col4 + 0) + w] = v.x;
        R0[SAF4(col4 + 1) + w] = v.y;
        R0[SAF4(col4 + 2) + w] = v.z;
        R0[SAF4(col4 + 3) + w] = v.w;
    }
    __syncthreads();

    const float4* f4 = reinterpret_cast<const float4*>(id2feat);
    const int* im = sIM + w * 32;
    const int* ia = sIA + w * 32;

    float acc[4][4] = {};
    float4 macc = make_float4(0.f, 0.f, 0.f, 0.f);

    // ---- phase 1: K-quarter [kq*64,+64) GEMM + interleaved mean gathers ----
    {
        float4 mr0[4], mr1[4];
#pragma unroll
        for (int j = 0; j < 4; ++j) mr0[j] = f4[(size_t)im[j] * 64 + l];
#pragma unroll
        for (int j = 0; j < 4; ++j) mr1[j] = f4[(size_t)im[4 + j] * 64 + l];

        const float* Bp = Wqk + (size_t)(kq * 64) * 256 + col4;
        float4 bufA[4], bufB[4];
#pragma unroll
        for (int j = 0; j < 4; ++j)
            bufA[j] = *reinterpret_cast<const float4*>(&Bp[(size_t)j * 256]);

#pragma unroll
        for (int ob = 0; ob < 4; ++ob) {
            const int k0 = ob * 16;
            // group 1: rows k0..k0+3
#pragma unroll
            for (int j = 0; j < 4; ++j)
                bufB[j] = *reinterpret_cast<const float4*>(&Bp[(size_t)(k0 + 4 + j) * 256]);
#pragma unroll
            for (int j = 0; j < 4; ++j) {
                const float4 a4 = *reinterpret_cast<const float4*>(&R0[SAF4(kq * 64 + k0 + j)]);
                FMA44(a4, bufA[j]);
            }
            // mean slot A: consume mr0 (rows ob*8..+3), reissue rows ob*8+8..+11
#pragma unroll
            for (int j = 0; j < 4; ++j) {
                macc.x += mr0[j].x; macc.y += mr0[j].y;
                macc.z += mr0[j].z; macc.w += mr0[j].w;
            }
            if (ob < 3) {
#pragma unroll
                for (int j = 0; j < 4; ++j)
                    mr0[j] = f4[(size_t)im[ob * 8 + 8 + j] * 64 + l];
            }
            // group 2: rows k0+4..7
#pragma unroll
            for (int j = 0; j < 4; ++j)
                bufA[j] = *reinterpret_cast<const float4*>(&Bp[(size_t)(k0 + 8 + j) * 256]);
#pragma unroll
            for (int j = 0; j < 4; ++j) {
                const float4 a4 =
                    *reinterpret_cast<const float4*>(&R0[SAF4(kq * 64 + k0 + 4 + j)]);
                FMA44(a4, bufB[j]);
            }
            // mean slot B: consume mr1 (rows ob*8+4..+7), reissue rows ob*8+12..+15
#pragma unroll
            for (int j = 0; j < 4; ++j) {
                macc.x += mr1[j].x; macc.y += mr1[j].y;
                macc.z += mr1[j].z; macc.w += mr1[j].w;
            }
            if (ob < 3) {
#pragma unroll
                for (int j = 0; j < 4; ++j)
                    mr1[j] = f4[(size_t)im[ob * 8 + 12 + j] * 64 + l];
            }
            // group 3: rows k0+8..11
#pragma unroll
            for (int j = 0; j < 4; ++j)
                bufB[j] = *reinterpret_cast<const float4*>(&Bp[(size_t)(k0 + 12 + j) * 256]);
#pragma unroll
            for (int j = 0; j < 4; ++j) {
                const float4 a4 =
                    *reinterpret_cast<const float4*>(&R0[SAF4(kq * 64 + k0 + 8 + j)]);
                FMA44(a4, bufA[j]);
            }
            // group 4: rows k0+12..15 (prefetch next ob's first group)
            if (ob < 3) {
#pragma unroll
                for (int j = 0; j < 4; ++j)
                    bufA[j] = *reinterpret_cast<const float4*>(&Bp[(size_t)(k0 + 16 + j) * 256]);
            }
#pragma unroll
            for (int j = 0; j < 4; ++j) {
                const float4 a4 =
                    *reinterpret_cast<const float4*>(&R0[SAF4(kq * 64 + k0 + 12 + j)]);
                FMA44(a4, bufB[j]);
            }
        }
    }

    // prefetch attn chunk 0 (latency drains during the combine barriers)
    float4 rA[8], rB[8];
#pragma unroll
    for (int j = 0; j < 8; ++j) rA[j] = f4[(size_t)ia[j] * 64 + l];

    __syncthreads();  // sA dead
    if (kq) {
        float* p = R0 + ((kq - 1) * 4) * 260 + col4;
#pragma unroll
        for (int r = 0; r < 4; ++r) {
            p[r * 260 + 0] = acc[r][0]; p[r * 260 + 1] = acc[r][1];
            p[r * 260 + 2] = acc[r][2]; p[r * 260 + 3] = acc[r][3];
        }
    }
    __syncthreads();
    if (kq == 0) {
        const float4 bq4 = *reinterpret_cast<const float4*>(&bqk[col4]);
#pragma unroll
        for (int r = 0; r < 4; ++r) {
            float v0 = acc[r][0] + bq4.x, v1 = acc[r][1] + bq4.y;
            float v2 = acc[r][2] + bq4.z, v3 = acc[r][3] + bq4.w;
#pragma unroll
            for (int s = 0; s < 3; ++s) {
                const float* p = R0 + (s * 4 + r) * 260 + col4;
                v0 += p[0]; v1 += p[1]; v2 += p[2]; v3 += p[3];
            }
            sQk[r * 260 + col4 + 0] = v0; sQk[r * 260 + col4 + 1] = v1;
            sQk[r * 260 + col4 + 2] = v2; sQk[r * 260 + col4 + 3] = v3;
        }
    }
    __syncthreads();  // sQk ready, sP dead

    // ---- phase 2: attn, double-buffered 8-row chunks, online softmax ----
    {
        const int b = w;
        const float4 q = *reinterpret_cast<const float4*>(&sQk[b * 260 + col4]);
        float m = -1e30f, e = 0.f;
        float4 wa = make_float4(0.f, 0.f, 0.f, 0.f);
#pragma unroll
        for (int c = 0; c < 4; ++c) {
            const float4* rc = (c & 1) ? rB : rA;
            float4* rn = (c & 1) ? rA : rB;
            if (c < 3) {
#pragma unroll
                for (int j = 0; j < 8; ++j)
                    rn[j] = f4[(size_t)ia[(c + 1) * 8 + j] * 64 + l];
            }
            float p[8];
#pragma unroll
            for (int j = 0; j < 8; ++j) {
                float s = q.x * rc[j].x + q.y * rc[j].y + q.z * rc[j].z + q.w * rc[j].w;
#pragma unroll
                for (int off = 32; off; off >>= 1) s += __shfl_xor(s, off);
                p[j] = s;
            }
            float cm = p[0];
#pragma unroll
            for (int j = 1; j < 8; ++j) cm = fmaxf(cm, p[j]);
            const float newm = fmaxf(m, cm);
            const float sc = __expf(m - newm);
            e *= sc; wa.x *= sc; wa.y *= sc; wa.z *= sc; wa.w *= sc;
#pragma unroll
            for (int j = 0; j < 8; ++j) {
                const float g = __expf(p[j] - newm);
                e += g;
                wa.x += g * rc[j].x; wa.y += g * rc[j].y;
                wa.z += g * rc[j].z; wa.w += g * rc[j].w;
            }
            m = newm;
        }
        const float inv = 1.0f / e;
        const float mixv[4] = {wa.x * inv, wa.y * inv, wa.z * inv, wa.w * inv};
        const float mev[4] = {macc.x * (1.f / 32), macc.y * (1.f / 32),
                              macc.z * (1.f / 32), macc.w * (1.f / 32)};
#pragma unroll
        for (int c = 0; c < 4; ++c) {
            R0[SAF4(col4 + c) + w] = mixv[c];
            R0[SAF4(256 + col4 + c) + w] = mev[c];
        }
    }

    // prefetch phase-3 B prologue (independent of sAF)
    const float* Bp3 = Wfused + (size_t)(kq * 128) * 256 + col4;
    float4 bufA[8], bufB[8];
#pragma unroll
    for (int j = 0; j < 8; ++j)
        bufA[j] = *reinterpret_cast<const float4*>(&Bp3[(size_t)j * 256]);
    __syncthreads();  // sAF ready

    // ---- phase 3: K-quarter [kq*128,+128) of AF(4x512)@Wfused ----
#pragma unroll
    for (int r = 0; r < 4; ++r)
#pragma unroll
        for (int c = 0; c < 4; ++c) acc[r][c] = 0.f;
    for (int kb = 0; kb < 128; kb += 16) {
#pragma unroll
        for (int j = 0; j < 8; ++j)
            bufB[j] = *reinterpret_cast<const float4*>(&Bp3[(size_t)(kb + 8 + j) * 256]);
#pragma unroll
        for (int j = 0; j < 8; ++j) {
            const float4 a4 = *reinterpret_cast<const float4*>(&R0[SAF4(kq * 128 + kb + j)]);
            FMA44(a4, bufA[j]);
        }
        if (kb + 16 < 128) {
#pragma unroll
            for (int j = 0; j < 8; ++j)
                bufA[j] = *reinterpret_cast<const float4*>(&Bp3[(size_t)(kb + 16 + j) * 256]);
        }
#pragma unroll
        for (int j = 0; j < 8; ++j) {
            const float4 a4 =
                *reinterpret_cast<const float4*>(&R0[SAF4(kq * 128 + kb + 8 + j)]);
            FMA44(a4, bufB[j]);
        }
    }
    __syncthreads();  // sAF dead
    if (kq) {
        float* p = R0 + ((kq - 1) * 4) * 260 + col4;
#pragma unroll
        for (int r = 0; r < 4; ++r) {
            p[r * 260 + 0] = acc[r][0]; p[r * 260 + 1] = acc[r][1];
            p[r * 260 + 2] = acc[r][2]; p[r * 260 + 3] = acc[r][3];
        }
    }
    __syncthreads();
    if (kq == 0) {
        const float4 bf4 = *reinterpret_cast<const float4*>(&bfull[col4]);
#pragma unroll
        for (int r = 0; r < 4; ++r) {
            float v0 = acc[r][0] + bf4.x, v1 = acc[r][1] + bf4.y;
            float v2 = acc[r][2] + bf4.z, v3 = acc[r][3] + bf4.w;
#pragma unroll
            for (int s = 0; s < 3; ++s) {
                const float* p = R0 + (s * 4 + r) * 260 + col4;
                v0 += p[0]; v1 += p[1]; v2 += p[2]; v3 += p[3];
            }
            v0 = tanhf(v0); v1 = tanhf(v1); v2 = tanhf(v2); v3 = tanhf(v3);
            float sq = v0 * v0 + v1 * v1 + v2 * v2 + v3 * v3;
#pragma unroll
            for (int off = 32; off; off >>= 1) sq += __shfl_xor(sq, off);
            const float invn = 1.0f / fmaxf(sqrtf(sq), 1e-12f);
            *reinterpret_cast<float4*>(&out[(size_t)(row0 + r) * 256 + col4]) =
                make_float4(v0 * invn, v1 * invn, v2 * invn, v3 * invn);
        }
    }
}

extern "C" void kernel_launch(void* const* d_in, const int* in_sizes, int n_in,
                              void* d_out, int out_size, void* d_ws, size_t ws_size,
                              hipStream_t stream) {
    const int* nodes      = (const int*)d_in[0];
    const int* neigh_mean = (const int*)d_in[1];
    const int* neigh_attn = (const int*)d_in[2];
    const float* id2feat  = (const float*)d_in[3];
    const float* Wm = (const float*)d_in[4];
    const float* bm = (const float*)d_in[5];
    const float* Wq = (const float*)d_in[6];
    const float* bq = (const float*)d_in[7];
    const float* Wk = (const float*)d_in[8];
    // d_in[9] = bk: cancels in softmax
    const float* Wv = (const float*)d_in[10];
    const float* bv = (const float*)d_in[11];
    const float* Wc = (const float*)d_in[12];
    const float* bc = (const float*)d_in[13];
    float* out = (float*)d_out;

    const int B = in_sizes[0];  // 4096

    float* ws    = (float*)d_ws;
    float* WkT   = ws;                 // 65536
    float* Wqk   = ws + 65536;         // 65536
    float* Wvc   = ws + 131072;        // 65536 } contiguous Wfused[512][256]
    float* Wmc   = ws + 196608;        // 65536 }
    float* bqk   = ws + 262144;        // 256
    float* bfull = ws + 262400;        // 256

    transpose256<<<dim3(8, 8), dim3(32, 8), 0, stream>>>(Wk, WkT);
    precompute3<<<dim3(32, 3), 256, 0, stream>>>(Wq, Wv, Wm, Wc, WkT, Wqk, Wvc, Wmc);
    bias_k<<<256, 256, 0, stream>>>(bq, bv, bm, bc, Wc, WkT, bqk, bfull);
    fused4<<<B / 4, 256, 0, stream>>>(id2feat, nodes, neigh_mean, neigh_attn,
                                      Wqk, bqk, Wvc /*Wfused*/, bfull, out);
}